// Round 10
// baseline (182.432 us; speedup 1.0000x reference)
//
#include <hip/hip_runtime.h>

#define N_HALF 8192
#define D 128
#define NJOBS 4224

typedef __bf16 bf16x8 __attribute__((ext_vector_type(8)));
typedef float f32x4 __attribute__((ext_vector_type(4)));

// ws layout (4327440 B):
// [0,       4194304)  bfS     -- bf16 features, MFMA-fragment-major:
//                        frag(T,kk,ni): elem ((T*4+kk)*4+ni)*512 + lane*8 + j
//                        holds row T*64+ni*16+l15, k = kk*32+quad*8+j
// [4194304, 4259840)  sq      (16384 f32)  -- exact fp32 |row|^2
// [4259840, 4292608)  U       (8192 f32)   -- rowsum_aa + rowsum_ab
// [4292608, 4325376)  V       (8192 f32)   -- colsum_ab + rowsum_bb
// [4325376, 4327424)  alignP  (512 f32)    -- per-prep-block align partials
// [4327424, 4327440)  ctr     (4 u32)      -- 0: job counter, 1: blocks-done
#define OFF_SQ 4194304
#define OFF_U  4259840
#define OFF_V  4292608
#define OFF_AL 4325376
#define OFF_CT 4327424

__device__ __forceinline__ unsigned short f2bf(float f) {
    unsigned int u = __float_as_uint(f);
    u += 0x7fffu + ((u >> 16) & 1u);   // round-to-nearest-even
    return (unsigned short)(u >> 16);
}

// ---- prep: block-local fragment emission (as R9) + counter zeroing
__global__ __launch_bounds__(256) void prep_kernel(
    const float* __restrict__ feats, unsigned short* __restrict__ bfS,
    float* __restrict__ sq, float* __restrict__ U, float* __restrict__ V,
    float* __restrict__ alignP, unsigned int* __restrict__ ctr)
{
    __shared__ float ld[32 * 132];
    __shared__ float nrm[32];
    __shared__ float alg[16];

    const int b = blockIdx.x;        // 0..511
    const int t = threadIdx.x;
    const int A0 = b * 16;

#pragma unroll
    for (int it = 0; it < 4; ++it) {
        int idx = it * 256 + t;
        int row = idx >> 5;
        int c4 = idx & 31;
        int grow = (row < 16) ? (A0 + row) : (N_HALF + A0 + row - 16);
        *(float4*)&ld[row * 132 + c4 * 4] =
            *(const float4*)(feats + (size_t)grow * D + c4 * 4);
    }
    if (t < 16)       U[A0 + t] = 0.f;
    else if (t < 32)  V[A0 + t - 16] = 0.f;
    if (b == 0 && t >= 32 && t < 36) ctr[t - 32] = 0u;
    __syncthreads();

    const int wave = t >> 6, lane = t & 63;
    {   // norms
        int r = 8 * wave + (lane >> 3);
        int k0 = (lane & 7) * 16;
        float s = 0.f;
#pragma unroll
        for (int k = 0; k < 16; k += 4) {
            float4 v = *(const float4*)&ld[r * 132 + k0 + k];
            s += v.x * v.x + v.y * v.y + v.z * v.z + v.w * v.w;
        }
        s += __shfl_xor(s, 1);
        s += __shfl_xor(s, 2);
        s += __shfl_xor(s, 4);
        if ((lane & 7) == 0) {
            nrm[r] = s;
            int grow = (r < 16) ? (A0 + r) : (N_HALF + A0 + r - 16);
            sq[grow] = s;
        }
    }
    __syncthreads();
    if (wave < 2) {   // exact diag alignment
        int r = 8 * wave + (lane >> 3);
        int k0 = (lane & 7) * 16;
        float s = 0.f;
#pragma unroll
        for (int k = 0; k < 16; k += 4) {
            float4 a = *(const float4*)&ld[r * 132 + k0 + k];
            float4 bb = *(const float4*)&ld[(r + 16) * 132 + k0 + k];
            s += a.x * bb.x + a.y * bb.y + a.z * bb.z + a.w * bb.w;
        }
        s += __shfl_xor(s, 1);
        s += __shfl_xor(s, 2);
        s += __shfl_xor(s, 4);
        if ((lane & 7) == 0) {
            float d2 = fmaxf(nrm[r] + nrm[r + 16] - 2.0f * s, 0.0f);
            alg[r] = -__logf(d2 + 1.0f);
        }
    }
    const int l = (t >> 2) & 15, j2 = t & 3, q = t >> 6;
    const int Ta = b >> 2, ni = b & 3;
#pragma unroll
    for (int kk = 0; kk < 4; ++kk) {
        float2 va = *(const float2*)&ld[l * 132 + kk * 32 + q * 8 + j2 * 2];
        float2 vb = *(const float2*)&ld[(l + 16) * 132 + kk * 32 + q * 8 + j2 * 2];
        unsigned int ua = ((unsigned int)f2bf(va.y) << 16) | f2bf(va.x);
        unsigned int ub = ((unsigned int)f2bf(vb.y) << 16) | f2bf(vb.x);
        ((unsigned int*)bfS)[((size_t)((Ta * 4 + kk) * 4 + ni)) * 256 + t] = ua;
        ((unsigned int*)bfS)[((size_t)(((128 + Ta) * 4 + kk) * 4 + ni)) * 256 + t] = ub;
    }
    __syncthreads();
    if (t == 0) {
        float s = 0.f;
#pragma unroll
        for (int r = 0; r < 16; ++r) s += alg[r];
        alignP[b] = s;
    }
}

// ---- persistent work-stealing matmul + fused tail. grid 512, no LDS in hot path.
__global__ __launch_bounds__(256, 2) void persist_kernel(
    const unsigned short* __restrict__ bfS, const float* __restrict__ sq,
    float* __restrict__ U, float* __restrict__ V,
    const float* __restrict__ alignP, unsigned int* __restrict__ ctr,
    unsigned int* __restrict__ out)
{
    const int wave = threadIdx.x >> 6, lane = threadIdx.x & 63;
    const int l15 = lane & 15, quad = lane >> 4;
    __shared__ int lastFlag;
    __shared__ float ps[4];

    for (;;) {
        int id;
        if (lane == 0) id = (int)atomicAdd(&ctr[0], 1u);
        id = __shfl(id, 0);
        if (id >= NJOBS) break;

        int kind, strip, js;
        if (id < 2048) {              // ab: column-chunk-major
            kind = 0; strip = id & 127; js = (id >> 7) * 8;
        } else {
            int t = id - 2048;
            kind = 1;
            if (t >= 1088) { t -= 1088; kind = 2; }
            int c = 0;
            while (t >= 8 * c + 8) { t -= 8 * c + 8; ++c; }   // <=15 iters
            strip = t; js = 8 * c;
        }
        const bool sym = (kind != 0);
        const int T_A = (kind == 2 ? 128 : 0) + strip;
        const int T_B0 = (kind == 1 ? 0 : 128);
        const int colSqB = (kind == 1 ? 0 : N_HALF);
        float* const rowDst = (kind == 2) ? V : U;
        float* const colDst = (kind == 1) ? U : V;

        // A fragments, scaled by -2 exactly: (x^0x8000)+0x0080 per bf16
        bf16x8 af[4][4];
#pragma unroll
        for (int mi = 0; mi < 4; ++mi)
#pragma unroll
            for (int kk = 0; kk < 4; ++kk) {
                union { uint4 u; bf16x8 v; } c;
                c.u = *(const uint4*)(bfS + ((size_t)((T_A * 4 + kk) * 4 + mi)) * 512 + lane * 8);
                c.u.x = (c.u.x ^ 0x80008000u) + 0x00800080u;
                c.u.y = (c.u.y ^ 0x80008000u) + 0x00800080u;
                c.u.z = (c.u.z ^ 0x80008000u) + 0x00800080u;
                c.u.w = (c.u.w ^ 0x80008000u) + 0x00800080u;
                af[mi][kk] = c.v;
            }
        float rs1[16];
#pragma unroll
        for (int mi = 0; mi < 4; ++mi)
#pragma unroll
            for (int r = 0; r < 4; ++r)
                rs1[mi * 4 + r] = sq[T_A * 64 + mi * 16 + quad * 4 + r] + 1.0f;

        float rowAcc[16];
#pragma unroll
        for (int x = 0; x < 16; ++x) rowAcc[x] = 0.f;

        const int je = js + 8;
        int j0 = js;
        if (sym && j0 < strip) j0 = strip;

        bf16x8 bbA[2][4], bbB[2][4];   // slices 0,1 and 2,3 of current tile
        auto loadPair = [&](int j, int s0, bf16x8 (*dst)[4]) {
#pragma unroll
            for (int s = 0; s < 2; ++s) {
                const unsigned short* p =
                    bfS + ((size_t)((T_B0 + j) * 4 + s0 + s)) * 2048 + lane * 8;
#pragma unroll
                for (int ni = 0; ni < 4; ++ni)
                    dst[s][ni] = *(const bf16x8*)(p + ni * 512);
            }
        };
        loadPair(j0, 0, bbA);
        loadPair(j0, 2, bbB);
        float csqN[4];
#pragma unroll
        for (int ni = 0; ni < 4; ++ni)
            csqN[ni] = sq[colSqB + j0 * 64 + ni * 16 + l15];

        for (int j = j0; j < je; ++j) {
            const int jn = (j + 1 < je) ? j + 1 : j;
            float csq[4] = {csqN[0], csqN[1], csqN[2], csqN[3]};

            // acc init = |a|^2 + |b|^2 + 1; MFMA adds -2*dot => acc = d2+1
            f32x4 acc[4][4];
#pragma unroll
            for (int mi = 0; mi < 4; ++mi)
#pragma unroll
                for (int ni = 0; ni < 4; ++ni)
#pragma unroll
                    for (int r = 0; r < 4; ++r)
                        acc[mi][ni][r] = rs1[mi * 4 + r] + csq[ni];

            // MFMA on slices 0,1; then refill bbA with next tile's 0,1
#pragma unroll
            for (int kk = 0; kk < 2; ++kk)
#pragma unroll
                for (int mi = 0; mi < 4; ++mi)
#pragma unroll
                    for (int ni = 0; ni < 4; ++ni)
                        acc[mi][ni] = __builtin_amdgcn_mfma_f32_16x16x32_bf16(
                            af[mi][kk], bbA[kk][ni], acc[mi][ni], 0, 0, 0);
            loadPair(jn, 0, bbA);
            // MFMA on slices 2,3; then refill bbB
#pragma unroll
            for (int kk = 0; kk < 2; ++kk)
#pragma unroll
                for (int mi = 0; mi < 4; ++mi)
#pragma unroll
                    for (int ni = 0; ni < 4; ++ni)
                        acc[mi][ni] = __builtin_amdgcn_mfma_f32_16x16x32_bf16(
                            af[mi][2 + kk], bbB[kk][ni], acc[mi][ni], 0, 0, 0);
            loadPair(jn, 2, bbB);
#pragma unroll
            for (int ni = 0; ni < 4; ++ni)
                csqN[ni] = sq[colSqB + jn * 64 + ni * 16 + l15];

            // epilogue (~600 VALU cyc) covers the just-issued loads
            const bool diag = sym && (j == strip);
            float colPart[4] = {0.f, 0.f, 0.f, 0.f};
#pragma unroll
            for (int mi = 0; mi < 4; ++mi)
#pragma unroll
                for (int ni = 0; ni < 4; ++ni)
#pragma unroll
                    for (int r = 0; r < 4; ++r) {
                        float sim = __builtin_amdgcn_rcpf(fmaxf(acc[mi][ni][r], 1.0f));
                        if (diag && (ni * 16 + l15) <= (mi * 16 + quad * 4 + r))
                            sim = 0.0f;   // strict upper only on diagonal tiles
                        rowAcc[mi * 4 + r] += sim;
                        colPart[ni] += sim;
                    }
#pragma unroll
            for (int ni = 0; ni < 4; ++ni) {
                float cv = colPart[ni];
                cv += __shfl_xor(cv, 16);
                cv += __shfl_xor(cv, 32);
                if (quad == 0) atomicAdd(&colDst[j * 64 + ni * 16 + l15], cv);
            }
        }
#pragma unroll
        for (int x = 0; x < 16; ++x) {
            float v = rowAcc[x];
            v += __shfl_xor(v, 1);
            v += __shfl_xor(v, 2);
            v += __shfl_xor(v, 4);
            v += __shfl_xor(v, 8);
            if (l15 == 0)
                atomicAdd(&rowDst[strip * 64 + (x >> 2) * 16 + quad * 4 + (x & 3)], v);
        }
    }

    // ---- fused tail: last block to finish reduces U/V (device-scope reads)
    __syncthreads();
    if (threadIdx.x == 0) {
        __threadfence();
        unsigned int old = atomicAdd(&ctr[1], 1u);
        lastFlag = (old == 511u);
    }
    __syncthreads();
    if (lastFlag) {
        float s = 0.f;
        for (int i = threadIdx.x; i < N_HALF; i += 256) {
            float u = __hip_atomic_load(&U[i], __ATOMIC_RELAXED, __HIP_MEMORY_SCOPE_AGENT);
            float v = __hip_atomic_load(&V[i], __ATOMIC_RELAXED, __HIP_MEMORY_SCOPE_AGENT);
            s += __logf(u) + __logf(v);
        }
        float a = 0.f;
        for (int i = threadIdx.x; i < 512; i += 256) a += alignP[i];
        float m = a - 0.5f * s;
#pragma unroll
        for (int off = 32; off; off >>= 1) m += __shfl_xor(m, off);
        if (lane == 0) ps[wave] = m;
        __syncthreads();
        if (threadIdx.x == 0) {
            float loss = -((ps[0] + ps[1] + ps[2] + ps[3]) / (float)N_HALF);
            unsigned int h = (unsigned int)f2bf(loss);
            out[0] = (h << 16) | h;   // fp32 reader: loss @ bf16 precision
        }
    }
}

extern "C" void kernel_launch(void* const* d_in, const int* in_sizes, int n_in,
                              void* d_out, int out_size, void* d_ws, size_t ws_size,
                              hipStream_t stream)
{
    const float* feats = (const float*)d_in[0];
    unsigned int* out = (unsigned int*)d_out;
    char* ws = (char*)d_ws;
    unsigned short* bfS = (unsigned short*)(ws);
    float* sq     = (float*)(ws + OFF_SQ);
    float* U      = (float*)(ws + OFF_U);
    float* V      = (float*)(ws + OFF_V);
    float* alignP = (float*)(ws + OFF_AL);
    unsigned int* ctr = (unsigned int*)(ws + OFF_CT);

    prep_kernel<<<512, 256, 0, stream>>>(feats, bfS, sq, U, V, alignP, ctr);
    persist_kernel<<<512, 256, 0, stream>>>(bfS, sq, U, V, alignP, ctr, out);
}

// Round 11
// 136.850 us; speedup vs baseline: 1.3331x; 1.3331x over previous
//
#include <hip/hip_runtime.h>

#define N_HALF 8192
#define D 128

typedef __bf16 bf16x8 __attribute__((ext_vector_type(8)));
typedef float f32x4 __attribute__((ext_vector_type(4)));

// ws layout (4327424 B):
// [0,       4194304)  bfS     -- bf16 features, MFMA-fragment-major:
//                        frag(T,kk,ni): elem ((T*4+kk)*4+ni)*512 + lane*8 + j
//                        holds row T*64+ni*16+(lane&15), k = kk*32+(lane>>4)*8+j
// [4194304, 4259840)  sq      (16384 f32)  -- exact fp32 |row|^2
// [4259840, 4292608)  U       (8192 f32)   -- rowsum_aa + rowsum_ab
// [4292608, 4325376)  V       (8192 f32)   -- colsum_ab + rowsum_bb
// [4325376, 4327424)  alignP  (512 f32)    -- per-prep-block align partials
#define OFF_SQ 4194304
#define OFF_U  4259840
#define OFF_V  4292608
#define OFF_AL 4325376

__device__ __forceinline__ unsigned short f2bf(float f) {
    unsigned int u = __float_as_uint(f);
    u += 0x7fffu + ((u >> 16) & 1u);   // round-to-nearest-even
    return (unsigned short)(u >> 16);
}

__device__ __forceinline__ void async_cp16(const unsigned short* g, unsigned short* l) {
    __builtin_amdgcn_global_load_lds(
        (const __attribute__((address_space(1))) void*)g,
        (__attribute__((address_space(3))) void*)l, 16, 0, 0);
}

// ---- prep: block-local fragment emission (proven R9 version)
__global__ __launch_bounds__(256) void prep_kernel(
    const float* __restrict__ feats, unsigned short* __restrict__ bfS,
    float* __restrict__ sq, float* __restrict__ U, float* __restrict__ V,
    float* __restrict__ alignP)
{
    __shared__ float ld[32 * 132];
    __shared__ float nrm[32];
    __shared__ float alg[16];

    const int b = blockIdx.x;        // 0..511
    const int t = threadIdx.x;
    const int A0 = b * 16;

#pragma unroll
    for (int it = 0; it < 4; ++it) {
        int idx = it * 256 + t;
        int row = idx >> 5;
        int c4 = idx & 31;
        int grow = (row < 16) ? (A0 + row) : (N_HALF + A0 + row - 16);
        *(float4*)&ld[row * 132 + c4 * 4] =
            *(const float4*)(feats + (size_t)grow * D + c4 * 4);
    }
    if (t < 16)       U[A0 + t] = 0.f;
    else if (t < 32)  V[A0 + t - 16] = 0.f;
    __syncthreads();

    const int wave = t >> 6, lane = t & 63;
    {   // norms
        int r = 8 * wave + (lane >> 3);
        int k0 = (lane & 7) * 16;
        float s = 0.f;
#pragma unroll
        for (int k = 0; k < 16; k += 4) {
            float4 v = *(const float4*)&ld[r * 132 + k0 + k];
            s += v.x * v.x + v.y * v.y + v.z * v.z + v.w * v.w;
        }
        s += __shfl_xor(s, 1);
        s += __shfl_xor(s, 2);
        s += __shfl_xor(s, 4);
        if ((lane & 7) == 0) {
            nrm[r] = s;
            int grow = (r < 16) ? (A0 + r) : (N_HALF + A0 + r - 16);
            sq[grow] = s;
        }
    }
    __syncthreads();
    if (wave < 2) {   // exact diag alignment term
        int r = 8 * wave + (lane >> 3);
        int k0 = (lane & 7) * 16;
        float s = 0.f;
#pragma unroll
        for (int k = 0; k < 16; k += 4) {
            float4 a = *(const float4*)&ld[r * 132 + k0 + k];
            float4 bb = *(const float4*)&ld[(r + 16) * 132 + k0 + k];
            s += a.x * bb.x + a.y * bb.y + a.z * bb.z + a.w * bb.w;
        }
        s += __shfl_xor(s, 1);
        s += __shfl_xor(s, 2);
        s += __shfl_xor(s, 4);
        if ((lane & 7) == 0) {
            float d2 = fmaxf(nrm[r] + nrm[r + 16] - 2.0f * s, 0.0f);
            alg[r] = -__logf(d2 + 1.0f);
        }
    }
    const int l = (t >> 2) & 15, j2 = t & 3, q = t >> 6;
    const int Ta = b >> 2, ni = b & 3;
#pragma unroll
    for (int kk = 0; kk < 4; ++kk) {
        float2 va = *(const float2*)&ld[l * 132 + kk * 32 + q * 8 + j2 * 2];
        float2 vb = *(const float2*)&ld[(l + 16) * 132 + kk * 32 + q * 8 + j2 * 2];
        unsigned int ua = ((unsigned int)f2bf(va.y) << 16) | f2bf(va.x);
        unsigned int ub = ((unsigned int)f2bf(vb.y) << 16) | f2bf(vb.x);
        ((unsigned int*)bfS)[((size_t)((Ta * 4 + kk) * 4 + ni)) * 256 + t] = ua;
        ((unsigned int*)bfS)[((size_t)(((128 + Ta) * 4 + kk) * 4 + ni)) * 256 + t] = ub;
    }
    __syncthreads();
    if (t == 0) {
        float s = 0.f;
#pragma unroll
        for (int r = 0; r < 16; ++r) s += alg[r];
        alignP[b] = s;
    }
}

// ---- band kernel: block = 128-row band x 8 col-tiles(64). 4 waves x 32 rows.
// A in regs (scaled -2); B staged ONCE per block per tile: 16KB contiguous DMA
// into LDS double-buffer (no swizzle; fragment-major), read via ds_read_b128.
// Order per step: barrier -> DMA(t+1) -> flush prev col-atomics -> compute.
// Jobs: ab 1024 + aa 544 + bb 544 = 2112 uniform 8-tile jobs.
__global__ __launch_bounds__(256, 4) void band_kernel(
    const unsigned short* __restrict__ bfS, const float* __restrict__ sq,
    float* __restrict__ U, float* __restrict__ V)
{
    __shared__ unsigned short lB[2][64 * D];   // 2 x 16 KB

    int kind, band, js;
    {
        int id = blockIdx.x;
        if (id < 1024) { kind = 0; band = id & 63; js = (id >> 6) * 8; }
        else {
            int t = id - 1024;
            kind = 1;
            if (t >= 544) { t -= 544; kind = 2; }
            int g = 0;
            while (t >= 4 * (16 - g)) { t -= 4 * (16 - g); ++g; }   // <=15 iters
            band = 4 * g + (t & 3);
            js = 8 * (g + (t >> 2));   // 8-aligned piece; covers diag tiles at p=0
        }
    }
    const int je = js + 8;
    const bool sym = (kind != 0);

    const int wave = threadIdx.x >> 6, lane = threadIdx.x & 63;
    const int l15 = lane & 15, quad = lane >> 4;

    const int T_Aw = (kind == 2 ? 128 : 0) + 2 * band + (wave >> 1);
    const int niA0 = (wave & 1) * 2;
    const int T_B0 = (kind == 1 ? 0 : 128);
    const int rowSqB = (kind == 2 ? N_HALF : 0);
    const int colSqB = (kind == 1 ? 0 : N_HALF);
    float* const rowDst = (kind == 2) ? V : U;
    float* const colDst = (kind == 1) ? U : V;
    const int wRow0 = band * 128 + wave * 32;   // wave's first row (local to half)

    // A fragments (32 rows), scaled by -2 exactly: (x^0x8000)+0x0080 per bf16
    bf16x8 af[2][4];
#pragma unroll
    for (int mi = 0; mi < 2; ++mi)
#pragma unroll
        for (int kk = 0; kk < 4; ++kk) {
            union { uint4 u; bf16x8 v; } c;
            c.u = *(const uint4*)(bfS + ((size_t)((T_Aw * 4 + kk) * 4 + niA0 + mi)) * 512 + lane * 8);
            c.u.x = (c.u.x ^ 0x80008000u) + 0x00800080u;
            c.u.y = (c.u.y ^ 0x80008000u) + 0x00800080u;
            c.u.z = (c.u.z ^ 0x80008000u) + 0x00800080u;
            c.u.w = (c.u.w ^ 0x80008000u) + 0x00800080u;
            af[mi][kk] = c.v;
        }

    float rs1[8];
#pragma unroll
    for (int mi = 0; mi < 2; ++mi)
#pragma unroll
        for (int r = 0; r < 4; ++r)
            rs1[mi * 4 + r] = sq[rowSqB + wRow0 + mi * 16 + quad * 4 + r] + 1.0f;

    float rowAcc[8];
#pragma unroll
    for (int x = 0; x < 8; ++x) rowAcc[x] = 0.f;

    // stage tile t: 16KB contiguous; wave w copies 4KB via 4 x 1KB DMA instrs
    auto stage = [&](int t, int s) {
        const unsigned short* src = bfS + ((size_t)(T_B0 + t)) * 8192 + wave * 2048 + lane * 8;
        unsigned short* dst = &lB[s][wave * 2048];
#pragma unroll
        for (int k = 0; k < 4; ++k)
            async_cp16(src + k * 512, dst + k * 512);
    };

    stage(js, 0);
    float csqN[4];
#pragma unroll
    for (int ni = 0; ni < 4; ++ni)
        csqN[ni] = sq[colSqB + js * 64 + ni * 16 + l15];

    float savedCol[4];
    int savedJ = -1;

    for (int t = js; t < je; ++t) {
        const int s = (t - js) & 1;
        __syncthreads();                    // drains DMA(t) + prev-step atomics (both ~1 step old)
        if (t + 1 < je) stage(t + 1, s ^ 1);

        // flush previous step's col atomics: a full step passes before next drain
        if (savedJ >= 0) {
#pragma unroll
            for (int ni = 0; ni < 4; ++ni) {
                float cv = savedCol[ni];
                cv += __shfl_xor(cv, 16);
                cv += __shfl_xor(cv, 32);
                if (quad == 0) atomicAdd(&colDst[savedJ + ni * 16 + l15], cv);
            }
            savedJ = -1;
        }

        const int jn = (t + 1 < je) ? t + 1 : t;
        float csq[4] = {csqN[0], csqN[1], csqN[2], csqN[3]};
#pragma unroll
        for (int ni = 0; ni < 4; ++ni)
            csqN[ni] = sq[colSqB + jn * 64 + ni * 16 + l15];

        if (sym && (t * 64 + 64) <= wRow0) continue;   // tile fully below wave's rows

        // acc init = |a|^2 + |b|^2 + 1; MFMA adds -2*dot => acc = d2+1
        f32x4 acc[2][4];
#pragma unroll
        for (int mi = 0; mi < 2; ++mi)
#pragma unroll
            for (int ni = 0; ni < 4; ++ni)
#pragma unroll
                for (int r = 0; r < 4; ++r)
                    acc[mi][ni][r] = rs1[mi * 4 + r] + csq[ni];

#pragma unroll
        for (int kk = 0; kk < 4; ++kk) {
            bf16x8 bfr[4];
#pragma unroll
            for (int ni = 0; ni < 4; ++ni)
                bfr[ni] = *(const bf16x8*)&lB[s][(kk * 4 + ni) * 512 + lane * 8];
#pragma unroll
            for (int mi = 0; mi < 2; ++mi)
#pragma unroll
                for (int ni = 0; ni < 4; ++ni)
                    acc[mi][ni] = __builtin_amdgcn_mfma_f32_16x16x32_bf16(
                        af[mi][kk], bfr[ni], acc[mi][ni], 0, 0, 0);
        }

        const bool maskDiag = sym && (t * 64 < wRow0 + 32);
        float colPart[4] = {0.f, 0.f, 0.f, 0.f};
#pragma unroll
        for (int mi = 0; mi < 2; ++mi)
#pragma unroll
            for (int ni = 0; ni < 4; ++ni)
#pragma unroll
                for (int r = 0; r < 4; ++r) {
                    float sim = __builtin_amdgcn_rcpf(fmaxf(acc[mi][ni][r], 1.0f));
                    if (maskDiag && (t * 64 + ni * 16 + l15) <= (wRow0 + mi * 16 + quad * 4 + r))
                        sim = 0.0f;   // strict upper only on diagonal-overlap tiles
                    rowAcc[mi * 4 + r] += sim;
                    colPart[ni] += sim;
                }
#pragma unroll
        for (int ni = 0; ni < 4; ++ni) savedCol[ni] = colPart[ni];
        savedJ = t * 64;
    }

    if (savedJ >= 0) {   // final col flush
#pragma unroll
        for (int ni = 0; ni < 4; ++ni) {
            float cv = savedCol[ni];
            cv += __shfl_xor(cv, 16);
            cv += __shfl_xor(cv, 32);
            if (quad == 0) atomicAdd(&colDst[savedJ + ni * 16 + l15], cv);
        }
    }
    // row flush: reduce over 16 l15 lanes, one atomic per row, once per job
#pragma unroll
    for (int x = 0; x < 8; ++x) {
        float v = rowAcc[x];
        v += __shfl_xor(v, 1);
        v += __shfl_xor(v, 2);
        v += __shfl_xor(v, 4);
        v += __shfl_xor(v, 8);
        if (l15 == 0)
            atomicAdd(&rowDst[wRow0 + (x >> 2) * 16 + quad * 4 + (x & 3)], v);
    }
}

// ---- tail: sum logs of U,V + align partials -> loss (single block)
__global__ __launch_bounds__(1024) void tail_kernel(
    const float* __restrict__ U, const float* __restrict__ V,
    const float* __restrict__ alignP, unsigned int* __restrict__ out)
{
    const int tid = threadIdx.x;
    float s = 0.f;
    const float4* U4 = (const float4*)U;
    const float4* V4 = (const float4*)V;
#pragma unroll
    for (int k = 0; k < 2; ++k) {
        float4 u = U4[tid * 2 + k];
        float4 v = V4[tid * 2 + k];
        s += __logf(u.x) + __logf(u.y) + __logf(u.z) + __logf(u.w);
        s += __logf(v.x) + __logf(v.y) + __logf(v.z) + __logf(v.w);
    }
    float a = 0.f;
    if (tid < 128) {
        float4 t4 = ((const float4*)alignP)[tid];
        a = t4.x + t4.y + t4.z + t4.w;
    }
    float m = a - 0.5f * s;
#pragma unroll
    for (int off = 32; off; off >>= 1) m += __shfl_xor(m, off);
    __shared__ float ps[16];
    if ((tid & 63) == 0) ps[tid >> 6] = m;
    __syncthreads();
    if (tid == 0) {
        float tot = 0.f;
#pragma unroll
        for (int w = 0; w < 16; ++w) tot += ps[w];
        float loss = -(tot / (float)N_HALF);
        unsigned int h = (unsigned int)f2bf(loss);
        out[0] = (h << 16) | h;   // fp32 reader: loss @ bf16 precision; bf16 reader: h
    }
}

extern "C" void kernel_launch(void* const* d_in, const int* in_sizes, int n_in,
                              void* d_out, int out_size, void* d_ws, size_t ws_size,
                              hipStream_t stream)
{
    const float* feats = (const float*)d_in[0];
    unsigned int* out = (unsigned int*)d_out;
    char* ws = (char*)d_ws;
    unsigned short* bfS = (unsigned short*)(ws);
    float* sq     = (float*)(ws + OFF_SQ);
    float* U      = (float*)(ws + OFF_U);
    float* V      = (float*)(ws + OFF_V);
    float* alignP = (float*)(ws + OFF_AL);

    prep_kernel<<<512, 256, 0, stream>>>(feats, bfS, sq, U, V, alignP);
    band_kernel<<<2112, 256, 0, stream>>>(bfS, sq, U, V);
    tail_kernel<<<1, 1024, 0, stream>>>(U, V, alignP, out);
}